// Round 4
// baseline (354.219 us; speedup 1.0000x reference)
//
#include <hip/hip_runtime.h>

// ---- hash / bucket constants ----
#define HBITS 19
#define HSIZE (1u << HBITS)
#define HMASK (HSIZE - 1u)
#define EMPTY_KEY 0xFFFFFFFFu
#define SLOTS 8   // direct slots per voxel; overflow (P~1e-4) goes to chain

__device__ __forceinline__ unsigned hash_key(unsigned k) {
    return (k * 2654435761u) >> (32 - HBITS);
}

__device__ __forceinline__ unsigned pack_key(int4 c) {
    // c.x = batch (<4), c.y/z/w = xyz in [0,256)
    return ((unsigned)c.x << 24) | ((unsigned)c.y << 16) |
           ((unsigned)c.z << 8) | (unsigned)c.w;
}

// Kernel A: insert voxel keys; htab[h] = (key, min original index).
__global__ __launch_bounds__(256)
void build_hash(const int4* __restrict__ tgt_coords, int M,
                uint2* __restrict__ htab) {
    int v = blockIdx.x * blockDim.x + threadIdx.x;
    if (v >= M) return;
    unsigned key = pack_key(tgt_coords[v]);
    unsigned h = hash_key(key);
    while (true) {
        unsigned prev = atomicCAS(&htab[h].x, EMPTY_KEY, key);
        if (prev == EMPTY_KEY || prev == key) {
            atomicMin(&htab[h].y, (unsigned)v);   // canonical = min index
            break;
        }
        h = (h + 1u) & HMASK;
    }
}

// Kernel A2: resolve canonical voxel index once per voxel.
__global__ __launch_bounds__(256)
void canonize(const int4* __restrict__ tgt_coords,
              const uint2* __restrict__ htab, int M,
              int* __restrict__ canon) {
    int v = blockIdx.x * blockDim.x + threadIdx.x;
    if (v >= M) return;
    unsigned key = pack_key(tgt_coords[v]);
    unsigned h = hash_key(key);
    uint2 e = htab[h];
    while (e.x != key) { h = (h + 1u) & HMASK; e = htab[h]; }
    canon[v] = (int)e.y;
}

// Kernel B: each point claims a bucket slot in its canonical voxel.
__global__ __launch_bounds__(256)
void fill_slots(const int* __restrict__ pts_idx,
                const int* __restrict__ canon,
                int BN,
                int* __restrict__ cnt,      // (M) init -1
                int* __restrict__ slotbuf,  // (M*SLOTS) no init needed
                int* __restrict__ ohead,    // (M) init -1
                int* __restrict__ nxt) {    // (BN) no init needed
    int p = blockIdx.x * blockDim.x + threadIdx.x;
    if (p >= BN) return;
    int c = canon[pts_idx[p]];
    int idx = atomicAdd(&cnt[c], 1) + 1;
    if (idx < SLOTS) slotbuf[c * SLOTS + idx] = p;
    else             nxt[p] = atomicExch(&ohead[c], p);   // rare
}

// Kernel E v4: FUSED gather + GEMV with FLAT WORKLIST gather.
// Round-3 post-mortem: VGPR=44 proved the compiler serialized the 8
// slot-row loads (load->wait->add x64 per block ~= 90us of chained HBM
// latency). v4 makes batching structural:
//  - pre-phase ballot-compacts the valid (voxel,slot) pairs (~128/block)
//    into an LDS worklist; tgt staged to xs[.][0:32]; mean region zeroed.
//  - flat loop: each 32-lane group takes items stride-8, manually 4-deep
//    batched into NAMED float2 regs (forced ILP), accumulates via
//    ds_add_f32 (LDS atomicAdd; avg contention 2; bank stride 2 benign).
//    ~4 batched latency waits per block instead of ~64 serial ones.
//  - phase 2: scalar-W GEMV (unchanged); mean = sum * inv at consumption
//    (identical rounding to storing the mean: one product rounding).
#define VOXB 64
#define XSTR 98   // even (float2-aligned); %32 banks=2 -> benign aliasing
__global__ __launch_bounds__(256, 4)
void gather_fuse(const float2* __restrict__ pf2,   // (BN,64) as (BN,32) float2
                 const float* __restrict__ tgtf,   // (M,32)
                 const int* __restrict__ cnt,
                 const int* __restrict__ slotbuf,  // (M*SLOTS) ints
                 const int* __restrict__ ohead,
                 const int* __restrict__ nxt,
                 const float* __restrict__ W,      // (96,32)
                 const float* __restrict__ bias,   // (32,)
                 int M,
                 float* __restrict__ out) {        // (M,32)
    __shared__ __align__(16) float xs[VOXB][XSTR];   // 25088 B
    __shared__ int scnt[VOXB];                       // 256 B
    __shared__ int wl[VOXB * SLOTS];                 // 2048 B
    __shared__ int wcnt;

    int t = threadIdx.x;
    int lane = t & 63;
    int vbase = blockIdx.x * VOXB;

    // ---- pre-phase A: metadata, zero-init, tgt staging (all coalesced) ----
    if (t == 0) wcnt = 0;
    if (t < VOXB) {
        int v = vbase + t;
        scnt[t] = (v < M) ? cnt[v] : -1;
    }
#pragma unroll
    for (int k = t; k < VOXB * 32; k += 256) {       // zero mean cols 32..96
        int vb = k >> 5, col = 32 + (k & 31) * 2;
        *reinterpret_cast<float2*>(&xs[vb][col]) = make_float2(0.f, 0.f);
    }
    {
        const float2* tg2 = reinterpret_cast<const float2*>(tgtf);
#pragma unroll
        for (int k = t; k < VOXB * 16; k += 256) {   // stage tgt cols 0..32
            int vb = k >> 4, idx = k & 15;
            int v = vbase + vb;
            float2 val = (v < M) ? tg2[(size_t)v * 16 + idx]
                                 : make_float2(0.f, 0.f);
            *reinterpret_cast<float2*>(&xs[vb][idx * 2]) = val;
        }
    }
    __syncthreads();   // scnt visible for worklist build

    // ---- pre-phase B: ballot-compact valid (vb,slot) -> point worklist ----
#pragma unroll
    for (int rnd = 0; rnd < 2; ++rnd) {
        int c = t + rnd * 256;                       // candidate 0..511
        int vb = c >> 3;
        int slot = c & 7;
        bool valid = (slot <= scnt[vb]);             // slot < n
        int p = 0;
        if (valid) p = slotbuf[(size_t)vbase * SLOTS + c];  // coalesced
        unsigned long long mask = __ballot(valid);
        int tot = __popcll(mask);
        int prefix = __popcll(mask & ((1ull << lane) - 1ull));
        int base = 0;
        if (lane == 0 && tot > 0) base = atomicAdd(&wcnt, tot);
        base = __shfl(base, 0);
        if (valid) wl[base + prefix] = (vb << 19) | p;   // p < 2^19
    }
    __syncthreads();   // wl, wcnt, xs init all visible

    int grp = t >> 5;
    int g   = t & 31;
    int nit = wcnt;

    // ---- phase 1: flat gather, 4-deep batched, ds_add_f32 accumulate ----
    int i = grp;
    for (; i + 24 < nit; i += 32) {
        int it0 = wl[i];
        int it1 = wl[i + 8];
        int it2 = wl[i + 16];
        int it3 = wl[i + 24];
        float2 f0 = pf2[(size_t)(it0 & 0x7FFFF) * 32 + g];
        float2 f1 = pf2[(size_t)(it1 & 0x7FFFF) * 32 + g];
        float2 f2 = pf2[(size_t)(it2 & 0x7FFFF) * 32 + g];
        float2 f3 = pf2[(size_t)(it3 & 0x7FFFF) * 32 + g];
        float* r0 = &xs[it0 >> 19][32 + 2 * g];
        float* r1 = &xs[it1 >> 19][32 + 2 * g];
        float* r2 = &xs[it2 >> 19][32 + 2 * g];
        float* r3 = &xs[it3 >> 19][32 + 2 * g];
        atomicAdd(r0, f0.x); atomicAdd(r0 + 1, f0.y);
        atomicAdd(r1, f1.x); atomicAdd(r1 + 1, f1.y);
        atomicAdd(r2, f2.x); atomicAdd(r2 + 1, f2.y);
        atomicAdd(r3, f3.x); atomicAdd(r3 + 1, f3.y);
    }
    for (; i < nit; i += 8) {
        int it = wl[i];
        float2 f = pf2[(size_t)(it & 0x7FFFF) * 32 + g];
        float* r = &xs[it >> 19][32 + 2 * g];
        atomicAdd(r, f.x); atomicAdd(r + 1, f.y);
    }

    // rare overflow chains (n > SLOTS)
    for (int vb = grp; vb < VOXB; vb += 8) {
        if (scnt[vb] + 1 > SLOTS) {
            int p = ohead[vbase + vb];
            float sx = 0.f, sy = 0.f;
            while (p >= 0) {
                float2 f = pf2[(size_t)p * 32 + g];
                sx += f.x; sy += f.y;
                p = nxt[p];
            }
            float* r = &xs[vb][32 + 2 * g];
            atomicAdd(r, sx); atomicAdd(r + 1, sy);
        }
    }
    __syncthreads();

    // ---- phase 2: GEMV, lane = voxel, wave = 8-channel block (scalar W) ----
    int vb2 = t & (VOXB - 1);
    int ocb = __builtin_amdgcn_readfirstlane((t >> 6) << 3);  // 0/8/16/24
    int v2  = vbase + vb2;
    if (v2 < M) {
        float inv = 1.0f / fmaxf((float)(scnt[vb2] + 1), 1.0f);
        float acc[8];
#pragma unroll
        for (int j = 0; j < 8; ++j) acc[j] = bias[ocb + j];

        // k = 0..31 (tgt region, unscaled) — FMA order matches reference path
#pragma unroll 4
        for (int k4 = 0; k4 < 8; ++k4) {
            float2 xa = *reinterpret_cast<const float2*>(&xs[vb2][k4 * 4]);
            float2 xb = *reinterpret_cast<const float2*>(&xs[vb2][k4 * 4 + 2]);
            const float* w0 = W + (k4 * 4 + 0) * 32 + ocb;
            const float* w1 = W + (k4 * 4 + 1) * 32 + ocb;
            const float* w2 = W + (k4 * 4 + 2) * 32 + ocb;
            const float* w3 = W + (k4 * 4 + 3) * 32 + ocb;
#pragma unroll
            for (int j = 0; j < 8; ++j) {
                acc[j] = fmaf(xa.x, w0[j], acc[j]);
                acc[j] = fmaf(xa.y, w1[j], acc[j]);
                acc[j] = fmaf(xb.x, w2[j], acc[j]);
                acc[j] = fmaf(xb.y, w3[j], acc[j]);
            }
        }
        // k = 32..95 (mean region: sum * inv, one product rounding = old mean)
#pragma unroll 4
        for (int k4 = 8; k4 < 24; ++k4) {
            float2 xa = *reinterpret_cast<const float2*>(&xs[vb2][k4 * 4]);
            float2 xb = *reinterpret_cast<const float2*>(&xs[vb2][k4 * 4 + 2]);
            float m0 = xa.x * inv, m1 = xa.y * inv;
            float m2 = xb.x * inv, m3 = xb.y * inv;
            const float* w0 = W + (k4 * 4 + 0) * 32 + ocb;
            const float* w1 = W + (k4 * 4 + 1) * 32 + ocb;
            const float* w2 = W + (k4 * 4 + 2) * 32 + ocb;
            const float* w3 = W + (k4 * 4 + 3) * 32 + ocb;
#pragma unroll
            for (int j = 0; j < 8; ++j) {
                acc[j] = fmaf(m0, w0[j], acc[j]);
                acc[j] = fmaf(m1, w1[j], acc[j]);
                acc[j] = fmaf(m2, w2[j], acc[j]);
                acc[j] = fmaf(m3, w3[j], acc[j]);
            }
        }

        float4* o = reinterpret_cast<float4*>(out + (size_t)v2 * 32 + ocb);
        o[0] = make_float4(acc[0], acc[1], acc[2], acc[3]);
        o[1] = make_float4(acc[4], acc[5], acc[6], acc[7]);
    }
}

extern "C" void kernel_launch(void* const* d_in, const int* in_sizes, int n_in,
                              void* d_out, int out_size, void* d_ws, size_t ws_size,
                              hipStream_t stream) {
    const float* pfeat      = (const float*)d_in[0];  // (BN,64)
    const float* tgt_feats  = (const float*)d_in[1];  // (M,32)
    const float* W_fuse     = (const float*)d_in[2];  // (96,32)
    const float* b_fuse     = (const float*)d_in[3];  // (32,)
    const int*   tgt_coords = (const int*)d_in[4];    // (M,4)
    const int*   pts_idx    = (const int*)d_in[5];    // (BN,)
    float* out = (float*)d_out;                       // (M,32)

    const int M  = in_sizes[4] / 4;
    const int BN = in_sizes[5];

    // workspace: [htab 4MB | cnt M | ohead M]  <- single 0xFF memset region
    //            [canon M | slotbuf M*8 | nxt BN] <- write-before-read
    char* ws = (char*)d_ws;
    uint2* htab    = (uint2*)ws;
    size_t off = (size_t)HSIZE * 8;
    int*   cnt     = (int*)(ws + off);              off += (size_t)M * 4;
    int*   ohead   = (int*)(ws + off);              off += (size_t)M * 4;
    int*   canon   = (int*)(ws + off);              off += (size_t)M * 4;
    int*   slotbuf = (int*)(ws + off);              off += (size_t)M * SLOTS * 4;
    int*   nxt     = (int*)(ws + off);

    size_t ff_bytes = (size_t)HSIZE * 8 + (size_t)M * 8;  // htab + cnt + ohead
    hipMemsetAsync(htab, 0xFF, ff_bytes, stream);  // EMPTY_KEY / UINT_MAX / -1

    const int TB = 256;
    build_hash<<<(M + TB - 1) / TB, TB, 0, stream>>>(
        (const int4*)tgt_coords, M, htab);
    canonize<<<(M + TB - 1) / TB, TB, 0, stream>>>(
        (const int4*)tgt_coords, htab, M, canon);
    fill_slots<<<(BN + TB - 1) / TB, TB, 0, stream>>>(
        pts_idx, canon, BN, cnt, slotbuf, ohead, nxt);
    gather_fuse<<<(M + VOXB - 1) / VOXB, TB, 0, stream>>>(
        (const float2*)pfeat, tgt_feats, cnt, slotbuf, ohead, nxt,
        W_fuse, b_fuse, M, out);
}

// Round 5
// 268.095 us; speedup vs baseline: 1.3212x; 1.3212x over previous
//
#include <hip/hip_runtime.h>

// ---- hash / bucket constants ----
#define HBITS 19
#define HSIZE (1u << HBITS)
#define HMASK (HSIZE - 1u)
#define EMPTY_KEY 0xFFFFFFFFu
#define SLOTS 8   // direct slots per voxel; overflow (P~1e-4) goes to chain

__device__ __forceinline__ unsigned hash_key(unsigned k) {
    return (k * 2654435761u) >> (32 - HBITS);
}

__device__ __forceinline__ unsigned pack_key(int4 c) {
    // c.x = batch (<4), c.y/z/w = xyz in [0,256)
    return ((unsigned)c.x << 24) | ((unsigned)c.y << 16) |
           ((unsigned)c.z << 8) | (unsigned)c.w;
}

// Kernel A: insert voxel keys; htab[h] = (key, min original index).
__global__ __launch_bounds__(256)
void build_hash(const int4* __restrict__ tgt_coords, int M,
                uint2* __restrict__ htab) {
    int v = blockIdx.x * blockDim.x + threadIdx.x;
    if (v >= M) return;
    unsigned key = pack_key(tgt_coords[v]);
    unsigned h = hash_key(key);
    while (true) {
        unsigned prev = atomicCAS(&htab[h].x, EMPTY_KEY, key);
        if (prev == EMPTY_KEY || prev == key) {
            atomicMin(&htab[h].y, (unsigned)v);   // canonical = min index
            break;
        }
        h = (h + 1u) & HMASK;
    }
}

// Kernel A2: resolve canonical voxel index once per voxel.
__global__ __launch_bounds__(256)
void canonize(const int4* __restrict__ tgt_coords,
              const uint2* __restrict__ htab, int M,
              int* __restrict__ canon) {
    int v = blockIdx.x * blockDim.x + threadIdx.x;
    if (v >= M) return;
    unsigned key = pack_key(tgt_coords[v]);
    unsigned h = hash_key(key);
    uint2 e = htab[h];
    while (e.x != key) { h = (h + 1u) & HMASK; e = htab[h]; }
    canon[v] = (int)e.y;
}

// Kernel B: each point claims a bucket slot in its canonical voxel.
__global__ __launch_bounds__(256)
void fill_slots(const int* __restrict__ pts_idx,
                const int* __restrict__ canon,
                int BN,
                int* __restrict__ cnt,      // (M) init -1
                int* __restrict__ slotbuf,  // (M*SLOTS) no init needed
                int* __restrict__ ohead,    // (M) init -1
                int* __restrict__ nxt) {    // (BN) no init needed
    int p = blockIdx.x * blockDim.x + threadIdx.x;
    if (p >= BN) return;
    int c = canon[pts_idx[p]];
    int idx = atomicAdd(&cnt[c], 1) + 1;
    if (idx < SLOTS) slotbuf[c * SLOTS + idx] = p;
    else             nxt[p] = atomicExch(&ohead[c], p);   // rare
}

// Kernel E v5: FUSED gather-mean + 96->32 GEMV.
// Round-4 post-mortem: worklist+LDS-atomics ADDED serialization (168us).
// Reverted to round-3 shape. The actual round-3 bottleneck (cross-round
// evidence r1 vs r3): the `if (n>k)` load ladder puts each slot-row load
// in its own conditional region -> compiler emits load->wait->add chains
// (VGPR=44 proves nothing kept in flight) -> ~64 serial HBM round trips
// per wave -> 733 GB/s ceiling. v5 fix:
//  - UNCONDITIONAL slot loads: slot index selected in VALU (invalid -> row
//    0), all 8 loads issued back-to-back (independent), contributions
//    masked by exact 0/1 AFTER the wait. f*0 = +0.0 exact, sum tree
//    unchanged -> bitwise-identical means to round 3.
//  - plain __launch_bounds__(256): LDS 27.4KB -> 5 blocks/CU (20 waves),
//    round-3's (256,4) had capped it at 4.
//  In-flight bytes/CU ~= 20 waves x 8 x 512B >> ~9KB needed for HBM sat.
#define VOXB 64
#define XSTR 98   // even (float2-aligned); %32 banks=2 -> mild 4-way on b64
__global__ __launch_bounds__(256)
void gather_fuse(const float2* __restrict__ pf2,   // (BN,64) as (BN,32) float2
                 const float* __restrict__ tgtf,   // (M,32)
                 const int* __restrict__ cnt,
                 const int4* __restrict__ slot4,   // slotbuf as (M,2) int4
                 const int* __restrict__ ohead,
                 const int* __restrict__ nxt,
                 const float* __restrict__ W,      // (96,32)
                 const float* __restrict__ bias,   // (32,)
                 int M,
                 float* __restrict__ out) {        // (M,32)
    __shared__ __align__(16) float xs[VOXB][XSTR];   // 25088 B
    __shared__ int scnt[VOXB];                       // 256 B
    __shared__ __align__(16) int4 sslot[VOXB * 2];   // 2048 B

    int t = threadIdx.x;
    int vbase = blockIdx.x * VOXB;

    // ---- pre-phase: coalesced slot-metadata staging ----
    if (t < VOXB) {
        int v = vbase + t;
        scnt[t] = (v < M) ? cnt[v] : -1;
    }
    if (t < VOXB * 2) {
        int j = vbase * 2 + t;
        sslot[t] = (j < M * 2) ? slot4[j] : make_int4(0, 0, 0, 0);
    }
    __syncthreads();

    int grp = t >> 5;
    int g   = t & 31;

    // ---- phase 1: gather-mean into LDS, 8 voxels per pass ----
    for (int pp = 0; pp < VOXB / 8; ++pp) {
        int vb = pp * 8 + grp;
        int v  = vbase + vb;
        if (v < M) {
            int n = scnt[vb] + 1;
            int4 sa = sslot[vb * 2];
            int4 sb = sslot[vb * 2 + 1];
            // select valid slot index (invalid -> row 0), then issue ALL
            // loads unconditionally & independently (the whole point).
            int p0 = (n > 0) ? sa.x : 0;
            int p1 = (n > 1) ? sa.y : 0;
            int p2 = (n > 2) ? sa.z : 0;
            int p3 = (n > 3) ? sa.w : 0;
            int p4 = (n > 4) ? sb.x : 0;
            int p5 = (n > 5) ? sb.y : 0;
            int p6 = (n > 6) ? sb.z : 0;
            int p7 = (n > 7) ? sb.w : 0;
            float2 f0 = pf2[(size_t)p0 * 32 + g];
            float2 f1 = pf2[(size_t)p1 * 32 + g];
            float2 f2 = pf2[(size_t)p2 * 32 + g];
            float2 f3 = pf2[(size_t)p3 * 32 + g];
            float2 f4 = pf2[(size_t)p4 * 32 + g];
            float2 f5 = pf2[(size_t)p5 * 32 + g];
            float2 f6 = pf2[(size_t)p6 * 32 + g];
            float2 f7 = pf2[(size_t)p7 * 32 + g];
            float tgv = tgtf[(size_t)v * 32 + g];
            float m0 = (n > 0) ? 1.f : 0.f;
            float m1 = (n > 1) ? 1.f : 0.f;
            float m2 = (n > 2) ? 1.f : 0.f;
            float m3 = (n > 3) ? 1.f : 0.f;
            float m4 = (n > 4) ? 1.f : 0.f;
            float m5 = (n > 5) ? 1.f : 0.f;
            float m6 = (n > 6) ? 1.f : 0.f;
            float m7 = (n > 7) ? 1.f : 0.f;
            float sx = ((f0.x * m0 + f1.x * m1) + (f2.x * m2 + f3.x * m3)) +
                       ((f4.x * m4 + f5.x * m5) + (f6.x * m6 + f7.x * m7));
            float sy = ((f0.y * m0 + f1.y * m1) + (f2.y * m2 + f3.y * m3)) +
                       ((f4.y * m4 + f5.y * m5) + (f6.y * m6 + f7.y * m7));
            if (n > SLOTS) {   // extremely rare overflow chain
                int p = ohead[v];
                while (p >= 0) {
                    float2 f = pf2[(size_t)p * 32 + g];
                    sx += f.x; sy += f.y;
                    p = nxt[p];
                }
            }
            float inv = 1.0f / fmaxf((float)n, 1.0f);
            xs[vb][g] = tgv;                                         // x[0..31]
            *reinterpret_cast<float2*>(&xs[vb][32 + 2 * g]) =
                make_float2(sx * inv, sy * inv);                     // x[32..95]
        }
    }

    __syncthreads();

    // ---- phase 2: GEMV, lane = voxel, wave = 8-channel block (scalar W) ----
    int vb2 = t & (VOXB - 1);
    int ocb = __builtin_amdgcn_readfirstlane((t >> 6) << 3);  // 0/8/16/24
    int v2  = vbase + vb2;
    if (v2 < M) {
        float acc[8];
#pragma unroll
        for (int j = 0; j < 8; ++j) acc[j] = bias[ocb + j];

#pragma unroll 4
        for (int k4 = 0; k4 < 24; ++k4) {
            float2 xa = *reinterpret_cast<const float2*>(&xs[vb2][k4 * 4]);
            float2 xb = *reinterpret_cast<const float2*>(&xs[vb2][k4 * 4 + 2]);
            const float* w0 = W + (k4 * 4 + 0) * 32 + ocb;
            const float* w1 = W + (k4 * 4 + 1) * 32 + ocb;
            const float* w2 = W + (k4 * 4 + 2) * 32 + ocb;
            const float* w3 = W + (k4 * 4 + 3) * 32 + ocb;
#pragma unroll
            for (int j = 0; j < 8; ++j) {
                acc[j] = fmaf(xa.x, w0[j], acc[j]);
                acc[j] = fmaf(xa.y, w1[j], acc[j]);
                acc[j] = fmaf(xb.x, w2[j], acc[j]);
                acc[j] = fmaf(xb.y, w3[j], acc[j]);
            }
        }

        float4* o = reinterpret_cast<float4*>(out + (size_t)v2 * 32 + ocb);
        o[0] = make_float4(acc[0], acc[1], acc[2], acc[3]);
        o[1] = make_float4(acc[4], acc[5], acc[6], acc[7]);
    }
}

extern "C" void kernel_launch(void* const* d_in, const int* in_sizes, int n_in,
                              void* d_out, int out_size, void* d_ws, size_t ws_size,
                              hipStream_t stream) {
    const float* pfeat      = (const float*)d_in[0];  // (BN,64)
    const float* tgt_feats  = (const float*)d_in[1];  // (M,32)
    const float* W_fuse     = (const float*)d_in[2];  // (96,32)
    const float* b_fuse     = (const float*)d_in[3];  // (32,)
    const int*   tgt_coords = (const int*)d_in[4];    // (M,4)
    const int*   pts_idx    = (const int*)d_in[5];    // (BN,)
    float* out = (float*)d_out;                       // (M,32)

    const int M  = in_sizes[4] / 4;
    const int BN = in_sizes[5];

    // workspace: [htab 4MB | cnt M | ohead M]  <- single 0xFF memset region
    //            [canon M | slotbuf M*8 | nxt BN] <- write-before-read
    char* ws = (char*)d_ws;
    uint2* htab    = (uint2*)ws;
    size_t off = (size_t)HSIZE * 8;
    int*   cnt     = (int*)(ws + off);              off += (size_t)M * 4;
    int*   ohead   = (int*)(ws + off);              off += (size_t)M * 4;
    int*   canon   = (int*)(ws + off);              off += (size_t)M * 4;
    int*   slotbuf = (int*)(ws + off);              off += (size_t)M * SLOTS * 4;
    int*   nxt     = (int*)(ws + off);

    size_t ff_bytes = (size_t)HSIZE * 8 + (size_t)M * 8;  // htab + cnt + ohead
    hipMemsetAsync(htab, 0xFF, ff_bytes, stream);  // EMPTY_KEY / UINT_MAX / -1

    const int TB = 256;
    build_hash<<<(M + TB - 1) / TB, TB, 0, stream>>>(
        (const int4*)tgt_coords, M, htab);
    canonize<<<(M + TB - 1) / TB, TB, 0, stream>>>(
        (const int4*)tgt_coords, htab, M, canon);
    fill_slots<<<(BN + TB - 1) / TB, TB, 0, stream>>>(
        pts_idx, canon, BN, cnt, slotbuf, ohead, nxt);
    gather_fuse<<<(M + VOXB - 1) / VOXB, TB, 0, stream>>>(
        (const float2*)pfeat, tgt_feats, cnt, (const int4*)slotbuf, ohead, nxt,
        W_fuse, b_fuse, M, out);
}

// Round 7
// 265.011 us; speedup vs baseline: 1.3366x; 1.0116x over previous
//
#include <hip/hip_runtime.h>

// ---- hash / bucket constants ----
#define HBITS 19
#define HSIZE (1u << HBITS)
#define HMASK (HSIZE - 1u)
#define EMPTY_KEY 0xFFFFFFFFu
#define SLOTS 8   // direct slots per voxel; overflow (P~1e-4) goes to chain

__device__ __forceinline__ unsigned hash_key(unsigned k) {
    return (k * 2654435761u) >> (32 - HBITS);
}

__device__ __forceinline__ unsigned pack_key(int4 c) {
    // c.x = batch (<4), c.y/z/w = xyz in [0,256)
    return ((unsigned)c.x << 24) | ((unsigned)c.y << 16) |
           ((unsigned)c.z << 8) | (unsigned)c.w;
}

// Kernel A: insert voxel keys; htab[h] = (key, min original index).
__global__ __launch_bounds__(256)
void build_hash(const int4* __restrict__ tgt_coords, int M,
                uint2* __restrict__ htab) {
    int v = blockIdx.x * blockDim.x + threadIdx.x;
    if (v >= M) return;
    unsigned key = pack_key(tgt_coords[v]);
    unsigned h = hash_key(key);
    while (true) {
        unsigned prev = atomicCAS(&htab[h].x, EMPTY_KEY, key);
        if (prev == EMPTY_KEY || prev == key) {
            atomicMin(&htab[h].y, (unsigned)v);   // canonical = min index
            break;
        }
        h = (h + 1u) & HMASK;
    }
}

// Kernel A2: resolve canonical voxel index once per voxel.
__global__ __launch_bounds__(256)
void canonize(const int4* __restrict__ tgt_coords,
              const uint2* __restrict__ htab, int M,
              int* __restrict__ canon) {
    int v = blockIdx.x * blockDim.x + threadIdx.x;
    if (v >= M) return;
    unsigned key = pack_key(tgt_coords[v]);
    unsigned h = hash_key(key);
    uint2 e = htab[h];
    while (e.x != key) { h = (h + 1u) & HMASK; e = htab[h]; }
    canon[v] = (int)e.y;
}

// Kernel B: each point claims a bucket slot in its canonical voxel.
__global__ __launch_bounds__(256)
void fill_slots(const int* __restrict__ pts_idx,
                const int* __restrict__ canon,
                int BN,
                int* __restrict__ cnt,      // (M) init -1
                int* __restrict__ slotbuf,  // (M*SLOTS) no init needed
                int* __restrict__ ohead,    // (M) init -1
                int* __restrict__ nxt) {    // (BN) no init needed
    int p = blockIdx.x * blockDim.x + threadIdx.x;
    if (p >= BN) return;
    int c = canon[pts_idx[p]];
    int idx = atomicAdd(&cnt[c], 1) + 1;
    if (idx < SLOTS) slotbuf[c * SLOTS + idx] = p;
    else             nxt[p] = atomicExch(&ohead[c], p);   // rare
}

// Kernel E v6 (resubmit — round-6 bench was an infra failure, not a
// kernel fault): FUSED gather-mean + 96->32 GEMV, REGISTER-DOUBLE-
// BUFFERED gather passes.
// Round-5 discriminator result: unconditional loads changed nothing
// (VGPR stayed 44 == exactly ONE pass of loads in flight). The wave sits
// in issue-8 -> wait-all -> consume, one pass deep; at loaded latency
// ~2500-3000cy that back-solves to the measured ~1.07TB/s delivered.
// v6 forces TWO passes in flight: loads for pass p+1 are issued in
// program order BEFORE pass p is consumed (named PassRegs A/B, no
// runtime-indexed arrays), so the compiler's counted vmcnt leaves the
// next pass outstanding across each consume. Sum tree / masks / GEMV
// bitwise-identical to round 5.
// Expected confirmation signal: VGPR ~70-90. If duration stays ~88 with
// the deeper pipeline, the random-256B pattern wall is real -> pivot to
// streaming-permute algorithm next.
#define VOXB 64
#define XSTR 98   // even (float2-aligned); %32 banks=2 -> benign aliasing
#define NPASS (VOXB / 8)

struct PassRegs {
    float2 f0, f1, f2, f3, f4, f5, f6, f7;
    float tgv;
    int n;
    int vb;
};

__device__ __forceinline__ void issue_pass(
    PassRegs& r, int pp, int grp, int g, int vbase, int M,
    const float2* __restrict__ pf2, const float* __restrict__ tgtf,
    const int* scnt, const int4* sslot) {
    int vb = pp * 8 + grp;
    int v  = vbase + vb;
    r.vb = vb;
    int n = scnt[vb] + 1;        // v>=M staged as cnt=-1 -> n=0 (all masked)
    r.n = n;
    int4 sa = sslot[vb * 2];
    int4 sb = sslot[vb * 2 + 1];
    int p0 = (n > 0) ? sa.x : 0;
    int p1 = (n > 1) ? sa.y : 0;
    int p2 = (n > 2) ? sa.z : 0;
    int p3 = (n > 3) ? sa.w : 0;
    int p4 = (n > 4) ? sb.x : 0;
    int p5 = (n > 5) ? sb.y : 0;
    int p6 = (n > 6) ? sb.z : 0;
    int p7 = (n > 7) ? sb.w : 0;
    // 8 independent row loads + tgt load, issued back-to-back
    r.f0 = pf2[(size_t)p0 * 32 + g];
    r.f1 = pf2[(size_t)p1 * 32 + g];
    r.f2 = pf2[(size_t)p2 * 32 + g];
    r.f3 = pf2[(size_t)p3 * 32 + g];
    r.f4 = pf2[(size_t)p4 * 32 + g];
    r.f5 = pf2[(size_t)p5 * 32 + g];
    r.f6 = pf2[(size_t)p6 * 32 + g];
    r.f7 = pf2[(size_t)p7 * 32 + g];
    int vc = (v < M) ? v : 0;    // clamp; xs write is guarded in consume
    r.tgv = tgtf[(size_t)vc * 32 + g];
}

__device__ __forceinline__ void consume_pass(
    const PassRegs& r, int g, int vbase, int M,
    const float2* __restrict__ pf2,
    const int* __restrict__ ohead, const int* __restrict__ nxt,
    float (*xs)[XSTR]) {
    int v = vbase + r.vb;
    if (v >= M) return;
    int n = r.n;
    float m0 = (n > 0) ? 1.f : 0.f;
    float m1 = (n > 1) ? 1.f : 0.f;
    float m2 = (n > 2) ? 1.f : 0.f;
    float m3 = (n > 3) ? 1.f : 0.f;
    float m4 = (n > 4) ? 1.f : 0.f;
    float m5 = (n > 5) ? 1.f : 0.f;
    float m6 = (n > 6) ? 1.f : 0.f;
    float m7 = (n > 7) ? 1.f : 0.f;
    float sx = ((r.f0.x * m0 + r.f1.x * m1) + (r.f2.x * m2 + r.f3.x * m3)) +
               ((r.f4.x * m4 + r.f5.x * m5) + (r.f6.x * m6 + r.f7.x * m7));
    float sy = ((r.f0.y * m0 + r.f1.y * m1) + (r.f2.y * m2 + r.f3.y * m3)) +
               ((r.f4.y * m4 + r.f5.y * m5) + (r.f6.y * m6 + r.f7.y * m7));
    if (n > SLOTS) {   // extremely rare overflow chain
        int p = ohead[v];
        while (p >= 0) {
            float2 f = pf2[(size_t)p * 32 + g];
            sx += f.x; sy += f.y;
            p = nxt[p];
        }
    }
    float inv = 1.0f / fmaxf((float)n, 1.0f);
    xs[r.vb][g] = r.tgv;                                     // x[0..31]
    *reinterpret_cast<float2*>(&xs[r.vb][32 + 2 * g]) =
        make_float2(sx * inv, sy * inv);                     // x[32..95]
}

__global__ __launch_bounds__(256)
void gather_fuse(const float2* __restrict__ pf2,   // (BN,64) as (BN,32) float2
                 const float* __restrict__ tgtf,   // (M,32)
                 const int* __restrict__ cnt,
                 const int4* __restrict__ slot4,   // slotbuf as (M,2) int4
                 const int* __restrict__ ohead,
                 const int* __restrict__ nxt,
                 const float* __restrict__ W,      // (96,32)
                 const float* __restrict__ bias,   // (32,)
                 int M,
                 float* __restrict__ out) {        // (M,32)
    __shared__ __align__(16) float xs[VOXB][XSTR];   // 25088 B
    __shared__ int scnt[VOXB];                       // 256 B
    __shared__ __align__(16) int4 sslot[VOXB * 2];   // 2048 B

    int t = threadIdx.x;
    int vbase = blockIdx.x * VOXB;

    // ---- pre-phase: coalesced slot-metadata staging ----
    if (t < VOXB) {
        int v = vbase + t;
        scnt[t] = (v < M) ? cnt[v] : -1;
    }
    if (t < VOXB * 2) {
        int j = vbase * 2 + t;
        sslot[t] = (j < M * 2) ? slot4[j] : make_int4(0, 0, 0, 0);
    }
    __syncthreads();

    int grp = t >> 5;
    int g   = t & 31;

    // ---- phase 1: register-double-buffered gather pipeline ----
    {
        PassRegs A, B;
        issue_pass(A, 0, grp, g, vbase, M, pf2, tgtf, scnt, sslot);
#pragma unroll
        for (int pp = 0; pp < NPASS; pp += 2) {
            if (pp + 1 < NPASS)
                issue_pass(B, pp + 1, grp, g, vbase, M, pf2, tgtf, scnt, sslot);
            consume_pass(A, g, vbase, M, pf2, ohead, nxt, xs);
            if (pp + 2 < NPASS)
                issue_pass(A, pp + 2, grp, g, vbase, M, pf2, tgtf, scnt, sslot);
            if (pp + 1 < NPASS)
                consume_pass(B, g, vbase, M, pf2, ohead, nxt, xs);
        }
    }

    __syncthreads();

    // ---- phase 2: GEMV, lane = voxel, wave = 8-channel block (scalar W) ----
    int vb2 = t & (VOXB - 1);
    int ocb = __builtin_amdgcn_readfirstlane((t >> 6) << 3);  // 0/8/16/24
    int v2  = vbase + vb2;
    if (v2 < M) {
        float acc[8];
#pragma unroll
        for (int j = 0; j < 8; ++j) acc[j] = bias[ocb + j];

#pragma unroll 4
        for (int k4 = 0; k4 < 24; ++k4) {
            float2 xa = *reinterpret_cast<const float2*>(&xs[vb2][k4 * 4]);
            float2 xb = *reinterpret_cast<const float2*>(&xs[vb2][k4 * 4 + 2]);
            const float* w0 = W + (k4 * 4 + 0) * 32 + ocb;
            const float* w1 = W + (k4 * 4 + 1) * 32 + ocb;
            const float* w2 = W + (k4 * 4 + 2) * 32 + ocb;
            const float* w3 = W + (k4 * 4 + 3) * 32 + ocb;
#pragma unroll
            for (int j = 0; j < 8; ++j) {
                acc[j] = fmaf(xa.x, w0[j], acc[j]);
                acc[j] = fmaf(xa.y, w1[j], acc[j]);
                acc[j] = fmaf(xb.x, w2[j], acc[j]);
                acc[j] = fmaf(xb.y, w3[j], acc[j]);
            }
        }

        float4* o = reinterpret_cast<float4*>(out + (size_t)v2 * 32 + ocb);
        o[0] = make_float4(acc[0], acc[1], acc[2], acc[3]);
        o[1] = make_float4(acc[4], acc[5], acc[6], acc[7]);
    }
}

extern "C" void kernel_launch(void* const* d_in, const int* in_sizes, int n_in,
                              void* d_out, int out_size, void* d_ws, size_t ws_size,
                              hipStream_t stream) {
    const float* pfeat      = (const float*)d_in[0];  // (BN,64)
    const float* tgt_feats  = (const float*)d_in[1];  // (M,32)
    const float* W_fuse     = (const float*)d_in[2];  // (96,32)
    const float* b_fuse     = (const float*)d_in[3];  // (32,)
    const int*   tgt_coords = (const int*)d_in[4];    // (M,4)
    const int*   pts_idx    = (const int*)d_in[5];    // (BN,)
    float* out = (float*)d_out;                       // (M,32)

    const int M  = in_sizes[4] / 4;
    const int BN = in_sizes[5];

    // workspace: [htab 4MB | cnt M | ohead M]  <- single 0xFF memset region
    //            [canon M | slotbuf M*8 | nxt BN] <- write-before-read
    char* ws = (char*)d_ws;
    uint2* htab    = (uint2*)ws;
    size_t off = (size_t)HSIZE * 8;
    int*   cnt     = (int*)(ws + off);              off += (size_t)M * 4;
    int*   ohead   = (int*)(ws + off);              off += (size_t)M * 4;
    int*   canon   = (int*)(ws + off);              off += (size_t)M * 4;
    int*   slotbuf = (int*)(ws + off);              off += (size_t)M * SLOTS * 4;
    int*   nxt     = (int*)(ws + off);

    size_t ff_bytes = (size_t)HSIZE * 8 + (size_t)M * 8;  // htab + cnt + ohead
    hipMemsetAsync(htab, 0xFF, ff_bytes, stream);  // EMPTY_KEY / UINT_MAX / -1

    const int TB = 256;
    build_hash<<<(M + TB - 1) / TB, TB, 0, stream>>>(
        (const int4*)tgt_coords, M, htab);
    canonize<<<(M + TB - 1) / TB, TB, 0, stream>>>(
        (const int4*)tgt_coords, htab, M, canon);
    fill_slots<<<(BN + TB - 1) / TB, TB, 0, stream>>>(
        pts_idx, canon, BN, cnt, slotbuf, ohead, nxt);
    gather_fuse<<<(M + VOXB - 1) / VOXB, TB, 0, stream>>>(
        (const float2*)pfeat, tgt_feats, cnt, (const int4*)slotbuf, ohead, nxt,
        W_fuse, b_fuse, M, out);
}